// Round 4
// baseline (1016.091 us; speedup 1.0000x reference)
//
#include <hip/hip_runtime.h>
#include <math.h>

#define NMS_THRESH 0.7f
#define NANCH 36864
#define TOPK 6000
#define NWORDS 94    // ceil(6000/64)
#define POSTK 300
#define MAXCAND 10240

// ---------------- conv 3x3 + bias + relu, batch 0 only ----------------
// grid 512 = y_tile(16) x co_tile(32), y-major for L2 reuse; block 256 (4 waves)
// block: 16 co x (4 rows x 64 cols). wave w owns co [co0+4w, +4) (uniform).
// thread: 4px x 4co. Weights via 1-ci-deep prefetched scalar loads.
// LDS: double-buffered halo-free tile [16ci][6rows][64cols]; edge cols
// (gx=-1, gx=64) are always outside the image -> synthesized 0 in registers.
__global__ __launch_bounds__(256, 2)
void k_conv(const float* __restrict__ feat, const float* __restrict__ W,
            const float* __restrict__ bias, float* __restrict__ tout)
{
    __shared__ float sS[2 * 16 * 6 * 64];   // 2 x 6144 floats = 48 KiB

    const int blk = blockIdx.x;
    const int ct  = blk & 31;             // co-tile 0..31
    const int yt  = blk >> 5;             // y-tile 0..15
    const int cob = ct << 4;
    const int y0  = yt << 2;
    const int tid = threadIdx.x;
    const int lane = tid & 63;
    const int wid = __builtin_amdgcn_readfirstlane(tid >> 6);
    const int co0 = cob + (wid << 2);
    const int ly = lane >> 4;             // row 0..3
    const int lx = (lane & 15) << 2;      // col 0..60 step 4

    // staging geometry: 6 float4 units per thread, constant across cc
    int g_ofs[6]; int l_ofs[6]; bool g_ok[6];
    #pragma unroll
    for (int q = 0; q < 6; ++q) {
        int u = q * 256 + tid;            // 0..1535
        int ci = u / 96; int rem = u - ci * 96;
        int rr = rem >> 4; int seg = rem & 15;
        int gy = y0 - 1 + rr;
        g_ok[q]  = (gy >= 0 && gy < 64);
        g_ofs[q] = (ci << 12) + ((gy & 63) << 6) + (seg << 2);
        l_ofs[q] = ci * 384 + (rr << 6) + (seg << 2);
    }

    const float* wbase = W + (size_t)co0 * 4608;   // uniform per wave
    float wA[36], wB[36];

#define LOADW(dst, cig) do {                                            \
        int _cg = (cig) < 512 ? (cig) : 511;                            \
        _Pragma("unroll")                                               \
        for (int _j = 0; _j < 4; ++_j) {                                \
            _Pragma("unroll")                                           \
            for (int _t = 0; _t < 9; ++_t)                              \
                dst[_j * 9 + _t] = wbase[(size_t)_j * 4608 + _cg * 9 + _t]; \
        }                                                               \
    } while (0)

    float acc[4][4];
    #pragma unroll
    for (int i = 0; i < 4; ++i)
        #pragma unroll
        for (int j = 0; j < 4; ++j) acc[i][j] = 0.f;

#define COMPUTE(ci, WREG) do {                                          \
        const float* _base = sS + pbase + (ci) * 384;                   \
        _Pragma("unroll")                                               \
        for (int ky = 0; ky < 3; ++ky) {                                \
            const float* _rb = _base + (ly + ky) * 64;                  \
            float4 _f4 = *(const float4*)&_rb[lx];                      \
            int _c0 = lx ? lx - 1 : 0;                                  \
            int _c5 = (lx < 60) ? lx + 4 : 63;                          \
            float _t0 = _rb[_c0];                                       \
            float _t5 = _rb[_c5];                                       \
            float fr[6];                                                \
            fr[0] = lx ? _t0 : 0.f;                                     \
            fr[1] = _f4.x; fr[2] = _f4.y; fr[3] = _f4.z; fr[4] = _f4.w; \
            fr[5] = (lx < 60) ? _t5 : 0.f;                              \
            _Pragma("unroll")                                           \
            for (int kx = 0; kx < 3; ++kx)                              \
                _Pragma("unroll")                                       \
                for (int i = 0; i < 4; ++i)                             \
                    _Pragma("unroll")                                   \
                    for (int j = 0; j < 4; ++j)                         \
                        acc[i][j] = fmaf(fr[i + kx], WREG[j * 9 + ky * 3 + kx], acc[i][j]); \
        }                                                               \
    } while (0)

    // prologue: stage cc=0 into buffer 0
    {
        float4 r[6];
        #pragma unroll
        for (int q = 0; q < 6; ++q)
            r[q] = g_ok[q] ? *(const float4*)(feat + g_ofs[q])
                           : make_float4(0.f, 0.f, 0.f, 0.f);
        #pragma unroll
        for (int q = 0; q < 6; ++q)
            *(float4*)&sS[l_ofs[q]] = r[q];
    }
    LOADW(wA, 0);
    __syncthreads();

    int p = 0;
    for (int cc = 0; cc < 32; ++cc) {
        const bool more = cc < 31;
        float4 r[6];
        if (more) {
            const float* fsrc = feat + ((size_t)(cc + 1) << 16);  // (cc+1)*16*4096
            #pragma unroll
            for (int q = 0; q < 6; ++q)
                r[q] = g_ok[q] ? *(const float4*)(fsrc + g_ofs[q])
                               : make_float4(0.f, 0.f, 0.f, 0.f);
        }
        const int pbase = p * 6144;
        const int cib = cc << 4;
        #pragma unroll
        for (int cp = 0; cp < 8; ++cp) {
            LOADW(wB, cib + 2 * cp + 1);
            COMPUTE(2 * cp, wA);
            LOADW(wA, cib + 2 * cp + 2);   // flows into next cc at cp==7
            COMPUTE(2 * cp + 1, wB);
        }
        if (more) {
            const int wb = (p ^ 1) * 6144;
            #pragma unroll
            for (int q = 0; q < 6; ++q)
                *(float4*)&sS[wb + l_ofs[q]] = r[q];
        }
        __syncthreads();
        p ^= 1;
    }

    const int y = y0 + ly;
    #pragma unroll
    for (int j = 0; j < 4; ++j) {
        const float bv = bias[co0 + j];
        float4 o;
        o.x = fmaxf(acc[0][j] + bv, 0.f);
        o.y = fmaxf(acc[1][j] + bv, 0.f);
        o.z = fmaxf(acc[2][j] + bv, 0.f);
        o.w = fmaxf(acc[3][j] + bv, 0.f);
        *(float4*)&tout[((size_t)(co0 + j) << 12) + (y << 6) + lx] = o;
    }
#undef LOADW
#undef COMPUTE
}

// ---------------- 1x1 heads: wave = 64 px of one channel ----------------
// grid 4096/64 * 45 = 2880 blocks x 64 threads; px-tile-major for L2 reuse
__global__ __launch_bounds__(64)
void k_heads(const float* __restrict__ t, const float* __restrict__ cls_w,
             const float* __restrict__ cls_b, const float* __restrict__ reg_w,
             const float* __restrict__ reg_b, float* __restrict__ heads)
{
    const int bid = blockIdx.x;
    const int ch = bid % 45;                  // uniform
    const int pt = bid / 45;
    const int px = (pt << 6) + threadIdx.x;
    const float* wp; float bv;
    if (ch < 9) { wp = cls_w + ch * 512;       bv = cls_b[ch]; }
    else        { wp = reg_w + (ch - 9) * 512; bv = reg_b[ch - 9]; }
    float acc = bv;
    #pragma unroll 8
    for (int ci = 0; ci < 512; ++ci)
        acc = fmaf(t[((size_t)ci << 12) + px], wp[ci], acc);
    heads[((size_t)ch << 12) + px] = acc;
}

// ---------------- decode + sigmoid + clip + validity + hist1 (fused) ----------------
__global__ void k_decode(const float* __restrict__ heads,
                         float* __restrict__ score, float* __restrict__ validf,
                         float* __restrict__ box, unsigned* __restrict__ hist)
{
    __shared__ unsigned lh[4096];
    const int tid = threadIdx.x;
    for (int q = tid; q < 4096; q += 256) lh[q] = 0u;
    __syncthreads();

    int idx = blockIdx.x * 256 + tid;
    int p = idx / 9, a = idx - p * 9;
    int yq = p >> 6, xq = p & 63;
    const double scl[3] = {128.0, 256.0, 512.0};
    const double rat[3] = {0.5, 1.0, 2.0};
    double s = scl[a / 3], r = rat[a % 3];
    float bw = (float)(s * sqrt(1.0 / r) * 0.5);
    float bh = (float)(s * sqrt(r) * 0.5);
    float sx = xq * 16.0f + 8.0f;
    float sy = yq * 16.0f + 8.0f;
    float a0 = sx - bw, a1 = sy - bh, a2 = sx + bw, a3 = sy + bh;
    float wa = a2 - a0, ha = a3 - a1;
    float cx = a0 + 0.5f * wa, cy = a1 + 0.5f * ha;
    float logit = heads[(size_t)a * 4096 + p];
    float dx = heads[(size_t)(9  + 4 * a) * 4096 + p];
    float dy = heads[(size_t)(10 + 4 * a) * 4096 + p];
    float dw = fminf(heads[(size_t)(11 + 4 * a) * 4096 + p], 4.135166556742356f);
    float dh = fminf(heads[(size_t)(12 + 4 * a) * 4096 + p], 4.135166556742356f);
    float pcx = dx * wa + cx, pcy = dy * ha + cy;
    float pw = expf(dw) * wa, ph = expf(dh) * ha;
    float x1 = pcx - 0.5f * pw, y1 = pcy - 0.5f * ph;
    float x2 = pcx + 0.5f * pw, y2 = pcy + 0.5f * ph;
    x1 = fminf(fmaxf(x1, 0.f), 1024.f); y1 = fminf(fmaxf(y1, 0.f), 1024.f);
    x2 = fminf(fmaxf(x2, 0.f), 1024.f); y2 = fminf(fmaxf(y2, 0.f), 1024.f);
    float wv = x2 - x1, hv = y2 - y1;
    float sc = 1.f / (1.f + expf(-logit));
    score[idx]  = sc;
    validf[idx] = (wv >= 1.f && hv >= 1.f) ? 1.f : 0.f;
    box[idx * 4 + 0] = x1; box[idx * 4 + 1] = y1;
    box[idx * 4 + 2] = x2; box[idx * 4 + 3] = y2;

    atomicAdd(&lh[__float_as_uint(sc) >> 19], 1u);
    __syncthreads();
    for (int q = tid; q < 4096; q += 256) if (lh[q]) atomicAdd(&hist[q], lh[q]);
}

// ---------------- top-k cutoff machinery ----------------
__global__ void k_zero(unsigned* __restrict__ p) {
    int i = blockIdx.x * 256 + threadIdx.x;
    if (i < 8448) p[i] = 0u;   // hist(4096) + hist2(4096) + meta
}

__global__ void k_cut1(const unsigned* __restrict__ hist, unsigned* __restrict__ meta) {
    __shared__ unsigned hh[4096];
    __shared__ unsigned gs[256];
    int tid = threadIdx.x;
    for (int q = tid; q < 4096; q += 256) hh[q] = hist[q];
    __syncthreads();
    unsigned s = 0;
    #pragma unroll
    for (int k = 0; k < 16; ++k) s += hh[tid * 16 + k];
    gs[tid] = s;
    __syncthreads();
    if (tid == 0) {
        unsigned cum = 0;
        for (int g = 255; g >= 0; --g) {
            if (cum + gs[g] >= (unsigned)TOPK) {
                for (int b = g * 16 + 15; b >= g * 16; --b) {
                    if (cum + hh[b] >= (unsigned)TOPK) { meta[2] = (unsigned)b; meta[3] = cum; break; }
                    cum += hh[b];
                }
                break;
            }
            cum += gs[g];
        }
    }
}

__global__ void k_hist2(const float* __restrict__ score, const unsigned* __restrict__ meta,
                        unsigned* __restrict__ hist2) {
    int idx = blockIdx.x * 256 + threadIdx.x;
    unsigned bits = __float_as_uint(score[idx]);
    if ((bits >> 19) == meta[2]) atomicAdd(&hist2[(bits >> 7) & 0xFFFu], 1u);
}

__global__ void k_cut2(const unsigned* __restrict__ hist2, unsigned* __restrict__ meta) {
    __shared__ unsigned hh[4096];
    __shared__ unsigned gs[256];
    int tid = threadIdx.x;
    for (int q = tid; q < 4096; q += 256) hh[q] = hist2[q];
    __syncthreads();
    unsigned s = 0;
    #pragma unroll
    for (int k = 0; k < 16; ++k) s += hh[tid * 16 + k];
    gs[tid] = s;
    __syncthreads();
    if (tid == 0) {
        unsigned cum = meta[3];
        unsigned B = meta[2];
        unsigned cut = B << 19;
        for (int g = 255; g >= 0; --g) {
            if (cum + gs[g] >= (unsigned)TOPK) {
                for (int b = g * 16 + 15; b >= g * 16; --b) {
                    cum += hh[b];
                    if (cum >= (unsigned)TOPK) { cut = (B << 19) | ((unsigned)b << 7); break; }
                }
                break;
            }
            cum += gs[g];
        }
        meta[0] = cut;
    }
}

__global__ void k_compact(const float* __restrict__ score, unsigned* __restrict__ meta,
                          int* __restrict__ cand, float* __restrict__ cscore) {
    int idx = blockIdx.x * 256 + threadIdx.x;
    unsigned bits = __float_as_uint(score[idx]);
    if (bits >= meta[0]) {
        unsigned pos = atomicAdd(&meta[1], 1u);
        if (pos < (unsigned)MAXCAND) {
            cand[pos] = idx;
            cscore[pos] = __uint_as_float(bits);
        }
    }
}

// ---------------- exact ranks, candidate-vs-candidate only ----------------
// valid because: any score strictly above a candidate's is itself >= cut,
// hence also a candidate (ties likewise). grid 320; block 256 = 32 x 8 splits.
__global__ __launch_bounds__(256, 4)
void k_rank(const float* __restrict__ score, const float* __restrict__ validf,
            const float* __restrict__ box, const unsigned* __restrict__ meta,
            const int* __restrict__ cand, const float* __restrict__ cscore,
            float* __restrict__ score6, float* __restrict__ sc6,
            float* __restrict__ box6)
{
    __shared__ int pc[8][32];
    const int tid = threadIdx.x;
    const int il = tid & 31, js = tid >> 5;
    unsigned ncand = meta[1]; if (ncand > (unsigned)MAXCAND) ncand = MAXCAND;
    const int c = blockIdx.x * 32 + il;
    int i = -1; float si = 0.f;
    if (c < (int)ncand) { i = cand[c]; si = cscore[c]; }
    int cnt = 0;
    {
        const float4* cs4 = (const float4*)cscore;
        const int4*   cd4 = (const int4*)cand;
        const int q0 = js * 320;                // 8 splits x 320 float4 = 10240
        for (int q = 0; q < 320; ++q) {
            float4 v = cs4[q0 + q];
            int4   w = cd4[q0 + q];
            cnt += (v.x > si) || (v.x == si && w.x < i);
            cnt += (v.y > si) || (v.y == si && w.y < i);
            cnt += (v.z > si) || (v.z == si && w.z < i);
            cnt += (v.w > si) || (v.w == si && w.w < i);
        }
    }
    pc[js][il] = cnt;
    __syncthreads();
    if (js == 0 && i >= 0) {
        int rank = 0;
        #pragma unroll
        for (int q = 0; q < 8; ++q) rank += pc[q][il];
        if (rank < TOPK) {
            score6[rank] = si;
            sc6[rank] = (validf[i] != 0.f) ? si : -INFINITY;
            box6[rank * 4 + 0] = box[i * 4 + 0];
            box6[rank * 4 + 1] = box[i * 4 + 1];
            box6[rank * 4 + 2] = box[i * 4 + 2];
            box6[rank * 4 + 3] = box[i * 4 + 3];
        }
    }
}

// ---------------- pairwise IoU bitmask ----------------
__global__ void k_iou(const float* __restrict__ box6,
                      unsigned long long* __restrict__ mask)
{
    __shared__ float jb[64][4];
    const int blk = blockIdx.x;
    const int rb = blk / NWORDS, wb = blk - rb * NWORDS;
    const int tid = threadIdx.x;
    int j = wb * 64 + tid;
    if (j < TOPK) {
        jb[tid][0] = box6[j * 4 + 0]; jb[tid][1] = box6[j * 4 + 1];
        jb[tid][2] = box6[j * 4 + 2]; jb[tid][3] = box6[j * 4 + 3];
    } else {
        jb[tid][0] = 0.f; jb[tid][1] = 0.f; jb[tid][2] = 0.f; jb[tid][3] = 0.f;
    }
    __syncthreads();
    int i = rb * 64 + tid;
    if (i >= TOPK) return;
    float x1 = box6[i * 4], y1 = box6[i * 4 + 1], x2 = box6[i * 4 + 2], y2 = box6[i * 4 + 3];
    float ai = (x2 - x1) * (y2 - y1);
    unsigned long long bits = 0;
    for (int q = 0; q < 64; ++q) {
        float bx1 = jb[q][0], by1 = jb[q][1], bx2 = jb[q][2], by2 = jb[q][3];
        float xl = fmaxf(x1, bx1), yt = fmaxf(y1, by1);
        float xr = fminf(x2, bx2), yb = fminf(y2, by2);
        float inter = fmaxf(xr - xl, 0.f) * fmaxf(yb - yt, 0.f);
        float aj = (bx2 - bx1) * (by2 - by1);
        float iou = inter / (ai + aj - inter);
        if (iou > NMS_THRESH) bits |= (1ull << q);
    }
    mask[(size_t)i * NWORDS + wb] = bits;
}

// ---------------- sequential greedy NMS scan + output ----------------
__global__ void k_scan(const float* __restrict__ sc6, const float* __restrict__ score6,
                       const float* __restrict__ box6,
                       const unsigned long long* __restrict__ mask,
                       float* __restrict__ out)
{
    __shared__ unsigned long long remv[NWORDS];
    __shared__ int kept[POSTK];
    __shared__ int kcnt;
    __shared__ int kbs_s;
    __shared__ int klist[64];
    const int tid = threadIdx.x;
    for (int w = tid; w < NWORDS; w += 256) remv[w] = 0ull;
    if (tid == 0) kcnt = 0;
    __syncthreads();
    for (int b = 0; b < NWORDS; ++b) {
        if (tid < 64) {
            int i = b * 64 + tid;
            bool v = (i < TOPK) && (sc6[i] > -INFINITY);
            unsigned long long mi = 0ull;
            if (v) mi = mask[(size_t)i * NWORDS + b];
            unsigned long long validb = __ballot(v);
            unsigned long long cur = remv[b];
            int kc = kcnt;
            int kb = 0;
            unsigned long long cand2 = validb & ~cur;
            while (cand2 != 0ull && kc < POSTK) {
                int rr = __builtin_ctzll(cand2);
                unsigned long long mr = __shfl(mi, rr, 64);
                if (tid == 0) { kept[kc] = b * 64 + rr; klist[kb] = rr; }
                ++kb; ++kc;
                cur |= mr | (1ull << rr);
                cand2 = validb & ~cur;
            }
            if (tid == 0) { kcnt = kc; kbs_s = kb; remv[b] = cur; }
        }
        __syncthreads();
        int kb = kbs_s;
        if (kb > 0) {
            int w = b + 1 + tid;
            if (w < NWORDS) {
                unsigned long long acc = remv[w];
                for (int q = 0; q < kb; ++q) {
                    int rr = klist[q];
                    acc |= mask[(size_t)(b * 64 + rr) * NWORDS + w];
                }
                remv[w] = acc;
            }
        }
        __syncthreads();
        if (kcnt >= POSTK) break;
    }
    __syncthreads();
    int kc = kcnt;
    for (int n = tid; n < POSTK; n += 256) {
        float o0 = 0.f, o1 = 0.f, o2 = 0.f, o3 = 0.f, o4 = 0.f;
        if (n < kc) {
            int i = kept[n];
            o0 = box6[i * 4 + 0]; o1 = box6[i * 4 + 1];
            o2 = box6[i * 4 + 2]; o3 = box6[i * 4 + 3];
            o4 = score6[i];
        }
        out[n * 5 + 0] = o0; out[n * 5 + 1] = o1; out[n * 5 + 2] = o2;
        out[n * 5 + 3] = o3; out[n * 5 + 4] = o4;
    }
}

extern "C" void kernel_launch(void* const* d_in, const int* in_sizes, int n_in,
                              void* d_out, int out_size, void* d_ws, size_t ws_size,
                              hipStream_t stream)
{
    (void)in_sizes; (void)n_in; (void)out_size; (void)ws_size;
    const float* feat   = (const float*)d_in[1];   // (8,512,64,64) -> batch 0 only
    const float* conv_w = (const float*)d_in[2];
    const float* conv_b = (const float*)d_in[3];
    const float* cls_w  = (const float*)d_in[4];
    const float* cls_b  = (const float*)d_in[5];
    const float* reg_w  = (const float*)d_in[6];
    const float* reg_b  = (const float*)d_in[7];

    char* ws = (char*)d_ws;
    float*    t      = (float*)(ws + 0);          // 8,388,608 B (dead after k_heads)
    float*    heads  = (float*)(ws + 8388608);    //   737,280 B
    unsigned* hist   = (unsigned*)(ws + 9125888); //    16,384 B
    unsigned* hist2  = (unsigned*)(ws + 9142272); //    16,384 B
    unsigned* meta   = (unsigned*)(ws + 9158656); // [0]=cut [1]=ncand [2]=bin [3]=above
    int*      cand   = (int*)(ws + 9158720);      //    40,960 B
    float*    cscore = (float*)(ws + 9199680);    //    40,960 B
    float*    score  = (float*)(ws + 9240640);    //   147,456 B
    float*    validf = (float*)(ws + 9388096);    //   147,456 B
    float*    box    = (float*)(ws + 9535552);    //   589,824 B
    float*    score6 = (float*)(ws + 10125376);   //    24,576 B
    float*    sc6    = (float*)(ws + 10149952);   //    24,576 B
    float*    box6   = (float*)(ws + 10174528);   //    96,000 B (end 10,270,528)
    unsigned long long* mask = (unsigned long long*)(ws + 0);  // reuse t: 4,512,000 B

    k_zero   <<<33,   256, 0, stream>>>(hist);
    k_conv   <<<512,  256, 0, stream>>>(feat, conv_w, conv_b, t);
    k_heads  <<<2880, 64,  0, stream>>>(t, cls_w, cls_b, reg_w, reg_b, heads);
    k_decode <<<144,  256, 0, stream>>>(heads, score, validf, box, hist);
    k_cut1   <<<1,    256, 0, stream>>>(hist, meta);
    k_hist2  <<<144,  256, 0, stream>>>(score, meta, hist2);
    k_cut2   <<<1,    256, 0, stream>>>(hist2, meta);
    k_compact<<<144,  256, 0, stream>>>(score, meta, cand, cscore);
    k_rank   <<<320,  256, 0, stream>>>(score, validf, box, meta, cand, cscore, score6, sc6, box6);
    k_iou    <<<NWORDS * NWORDS, 64, 0, stream>>>(box6, mask);
    k_scan   <<<1,    256, 0, stream>>>(sc6, score6, box6, mask, (float*)d_out);
}